// Round 8
// baseline (114.879 us; speedup 1.0000x reference)
//
#include <hip/hip_runtime.h>
#include <hip/hip_bf16.h>

// Problem constants (from reference setup_inputs)
#define RR 3
#define BB 2
#define NN 2048
#define DD 128
#define HH 4
#define HD 32
#define LEAKY 0.2f
#define LN_EPS 1e-5f
#define LOG2E 1.4426950408889634f

using f32x4  = __attribute__((ext_vector_type(4))) float;
using bf16x8 = __attribute__((ext_vector_type(8))) short;

__device__ __forceinline__ void gload_lds16(const void* g, void* l) {
    __builtin_amdgcn_global_load_lds(
        (const __attribute__((address_space(1))) unsigned*)g,
        (__attribute__((address_space(3))) unsigned*)l, 16, 0, 0);
}
__device__ __forceinline__ void gload_lds4(const void* g, void* l) {
    __builtin_amdgcn_global_load_lds(
        (const __attribute__((address_space(1))) unsigned*)g,
        (__attribute__((address_space(3))) unsigned*)l, 4, 0, 0);
}

// ---------------------------------------------------------------------------
// Kernel 1: fused prep, 16 KB LDS (occupancy-friendly for the BW-bound role).
// 3840 blocks, 4:1 interleaved roles:
//  - 3072 "compact" blocks: A (100.7 MB int32) -> bitmask (3.1 MB). BW-bound,
//    zero LDS use, needs high occupancy -> LDS kept at 16 KB total.
//  - 768 "wh" blocks: Wh = H@W per (r,b,h); whT bf16 [rbh][f][n]; es/ed
//    (log2e-scaled). Ws staged in LDS; H read via L1-broadcast float4 loads
//    (same addr across the 32 f-lanes of a half-wave; 32 KB tile is L1-hot).
// ---------------------------------------------------------------------------
__global__ __launch_bounds__(256) void prep_kernel(
    const float* __restrict__ H, const int* __restrict__ A,
    const float* __restrict__ W,
    const float* __restrict__ a_src, const float* __restrict__ a_dst,
    float* __restrict__ es, float* __restrict__ ed,
    __hip_bfloat16* __restrict__ whT, unsigned* __restrict__ bm)
{
    __shared__ __align__(16) float Ws[128 * 32];   // 16 KB only

    const int g5 = blockIdx.x / 5, pos = blockIdx.x % 5;
    const int t  = threadIdx.x;

    if (pos < 4) {
        // ---- compact role ----
        const long gw = ((long)(g5 * 4 + pos)) * 256 + t;   // bitmask word index
        const int4* p = (const int4*)(A + gw * 32);
        unsigned wmask = 0;
#pragma unroll
        for (int k = 0; k < 8; ++k) {
            int4 v = p[k];
            wmask |= (v.x != 0 ? 1u : 0u) << (k * 4 + 0);
            wmask |= (v.y != 0 ? 1u : 0u) << (k * 4 + 1);
            wmask |= (v.z != 0 ? 1u : 0u) << (k * 4 + 2);
            wmask |= (v.w != 0 ? 1u : 0u) << (k * 4 + 3);
        }
        bm[gw] = wmask;
        return;
    }

    // ---- wh role ----
    const int bid = g5;               // 0..767
    const int nt = bid & 31;
    const int h  = (bid >> 5) & 3;
    const int b  = (bid >> 7) & 1;
    const int r  = bid >> 8;
    const int n0 = nt << 6;

    const float* Wb = W + (long)(r * HH + h) * DD * HD;
#pragma unroll
    for (int k = 0; k < 4; ++k) {
        int f4 = t + 256 * k;
        ((float4*)Ws)[f4] = ((const float4*)Wb)[f4];
    }
    __syncthreads();

    const int f  = t & 31;
    const int rg = t >> 5;
    const float av = a_src[(r * HH + h) * HD + f] * LOG2E;
    const float dv = a_dst[(r * HH + h) * HD + f] * LOG2E;
    const int rbh = (r * BB + b) * HH + h;

#pragma unroll
    for (int k = 0; k < 8; ++k) {
        const int row = rg * 8 + k;
        const float4* hrow = (const float4*)(H + ((long)b * NN + n0 + row) * DD);
        float acc = 0.0f;
#pragma unroll
        for (int d4 = 0; d4 < 32; ++d4) {
            float4 hv = hrow[d4];          // broadcast across the 32 f-lanes
            acc += hv.x * Ws[(d4 * 4 + 0) * 32 + f];
            acc += hv.y * Ws[(d4 * 4 + 1) * 32 + f];
            acc += hv.z * Ws[(d4 * 4 + 2) * 32 + f];
            acc += hv.w * Ws[(d4 * 4 + 3) * 32 + f];
        }
        whT[((long)rbh * HD + f) * NN + n0 + row] = __float2bfloat16(acc);
        float s = acc * av;
        float d = acc * dv;
#pragma unroll
        for (int m = 1; m < 32; m <<= 1) {
            s += __shfl_xor(s, m);
            d += __shfl_xor(d, m);
        }
        if (f == 0) {
            es[(long)rbh * NN + n0 + row] = s;
            ed[(long)rbh * NN + n0 + row] = d;
        }
    }
}

// ---------------------------------------------------------------------------
// Kernel 2: fused masked softmax + MFMA aggregation.
// block = (r,b,h, 128 i-rows, j-half of 1024). 4 waves; each wave owns TWO
// 16-row i-subtiles (rows w*16 and 64+w*16) -> every staged whT/ed byte is
// used twice. 8 double-buffered stages of 128 j via global_load_lds with
// per-wave counted vmcnt(5) and RAW s_barrier (no compiler vmcnt(0) drain).
// Row-max bound computed in-kernel from ed (any upper bound cancels exactly).
// grid = R*B*HH*16*2 = 768 blocks (XCD-chunk swizzled), 256 threads.
// ---------------------------------------------------------------------------
__global__ __launch_bounds__(256, 3) void gat_attn_kernel(
    const unsigned* __restrict__ bm, const float* __restrict__ es,
    const float* __restrict__ ed, const __hip_bfloat16* __restrict__ whT,
    float* __restrict__ num, float* __restrict__ den)
{
    // XCD-chunked bijective swizzle (768 % 8 == 0)
    const int lg = ((int)blockIdx.x % 8) * 96 + (int)blockIdx.x / 8;
    const int jh = lg & 1;
    const int it = (lg >> 1) & 15;         // 16 tiles of 128 rows
    const int h  = (lg >> 5) & 3;
    const int b  = (lg >> 7) & 1;
    const int r  = lg >> 8;
    const int i0 = it << 7;
    const int tid = threadIdx.x;
    const int w = tid >> 6;
    const int l = tid & 63;
    const int row = l & 15;                // A-frag row / B-frag f-col
    const int kg  = l >> 4;                // k-octet
    const int f31 = l & 31;
    const int kgr = l >> 5;

    __shared__ __align__(16) short    whs[2][4][4][32][8]; // [buf][jc][kg][f][8] : 16 KB
    __shared__ __align__(16) unsigned bms[2][4][128];      // [buf][jc][blockrow] : 4 KB
    __shared__ __align__(16) float    eds[2][4][32];       // [buf][jc][j]        : 1 KB
    __shared__ float red[4];

    const int rbh = (r * BB + b) * HH + h;
    const long rbNN = (long)(r * BB + b) * NN;
    const __hip_bfloat16* whTr = whT + (long)rbh * HD * NN;
    const float* edr = ed + (long)rbh * NN;
    const int jbase = jh * (NN / 2);

#define STAGE(s, nb) do {                                                           \
        const int j0s = jbase + (s) * 128;                                          \
        gload_lds16(whTr + (long)f31 * NN + j0s + w * 32 + kgr * 8,                 \
                    &whs[nb][w][0][0][0]);                                          \
        gload_lds16(whTr + (long)f31 * NN + j0s + w * 32 + (2 + kgr) * 8,           \
                    &whs[nb][w][2][0][0]);                                          \
        gload_lds4(bm + (rbNN + i0 + l) * (NN / 32) + (j0s >> 5) + w,               \
                   &bms[nb][w][0]);                                                 \
        gload_lds4(bm + (rbNN + i0 + 64 + l) * (NN / 32) + (j0s >> 5) + w,          \
                   &bms[nb][w][64]);                                                \
        if (l < 32) gload_lds4(edr + j0s + w * 32 + l, &eds[nb][w][0]);             \
    } while (0)

    STAGE(0, 0);   // issue first stage before the med reduce (latency overlap)

    // block-wide max of ed over all 2048 j (upper bound; cancels in num/den)
    float4 m0 = ((const float4*)edr)[tid * 2];
    float4 m1 = ((const float4*)edr)[tid * 2 + 1];
    float mm = fmaxf(fmaxf(fmaxf(m0.x, m0.y), fmaxf(m0.z, m0.w)),
                     fmaxf(fmaxf(m1.x, m1.y), fmaxf(m1.z, m1.w)));
#pragma unroll
    for (int d = 1; d < 64; d <<= 1) mm = fmaxf(mm, __shfl_xor(mm, d));
    if (l == 0) red[w] = mm;
    __syncthreads();
    const float medf = fmaxf(fmaxf(red[0], red[1]), fmaxf(red[2], red[3]));

    // per-row softmax constants for the two subtiles (log2e-scaled domain)
    const float esvA = es[(long)rbh * NN + i0 + w * 16 + row];
    const float esvB = es[(long)rbh * NN + i0 + 64 + w * 16 + row];
    const float xA = esvA + medf, xB = esvB + medf;
    const float MA = fmaxf(xA, LEAKY * xA), MB = fmaxf(xB, LEAKY * xB);
    const float uA = esvA - MA, vA = fmaf(LEAKY, esvA, -MA);
    const float uB = esvB - MB, vB = fmaf(LEAKY, esvB, -MB);

    f32x4 acc0A = {0,0,0,0}, acc1A = {0,0,0,0}, accDA = {0,0,0,0};
    f32x4 acc0B = {0,0,0,0}, acc1B = {0,0,0,0}, accDB = {0,0,0,0};
    bf16x8 ones;
#pragma unroll
    for (int i = 0; i < 8; ++i) ones[i] = (short)0x3F80;   // bf16 1.0

    for (int s = 0; s < 8; ++s) {
        const int cb = s & 1, nb = cb ^ 1;
        if (s < 7) {
            STAGE(s + 1, nb);
            asm volatile("s_waitcnt vmcnt(5)" ::: "memory");
        } else {
            asm volatile("s_waitcnt vmcnt(0)" ::: "memory");
        }
        __builtin_amdgcn_s_barrier();
        __builtin_amdgcn_sched_barrier(0);

#pragma unroll
        for (int jc = 0; jc < 4; ++jc) {
            bf16x8 b0 = *(const bf16x8*)&whs[cb][jc][kg][row][0];
            bf16x8 b1 = *(const bf16x8*)&whs[cb][jc][kg][row + 16][0];
            float4 e0 = *(const float4*)&eds[cb][jc][kg * 8];
            float4 e1 = *(const float4*)&eds[cb][jc][kg * 8 + 4];
            const unsigned mybA = (bms[cb][jc][w * 16 + row] >> (kg * 8)) & 0xffu;
            const unsigned mybB = (bms[cb][jc][64 + w * 16 + row] >> (kg * 8)) & 0xffu;

            float ev[8];
            ev[0] = e0.x; ev[1] = e0.y; ev[2] = e0.z; ev[3] = e0.w;
            ev[4] = e1.x; ev[5] = e1.y; ev[6] = e1.z; ev[7] = e1.w;

            bf16x8 pA, pB;
#pragma unroll
            for (int c = 0; c < 8; ++c) {
                float pa = __builtin_amdgcn_exp2f(
                    fmaxf(uA + ev[c], fmaf(LEAKY, ev[c], vA)));
                float pb = __builtin_amdgcn_exp2f(
                    fmaxf(uB + ev[c], fmaf(LEAKY, ev[c], vB)));
                const int ma = ((int)(mybA << (31 - c))) >> 31;   // v_bfe_i32
                const int mb = ((int)(mybB << (31 - c))) >> 31;
                pa = __uint_as_float(__float_as_uint(pa) & (unsigned)ma);
                pb = __uint_as_float(__float_as_uint(pb) & (unsigned)mb);
                __hip_bfloat16 ha = __float2bfloat16(pa);
                __hip_bfloat16 hb = __float2bfloat16(pb);
                pA[c] = __builtin_bit_cast(short, ha);
                pB[c] = __builtin_bit_cast(short, hb);
            }

            acc0A = __builtin_amdgcn_mfma_f32_16x16x32_bf16(pA, b0, acc0A, 0, 0, 0);
            acc1A = __builtin_amdgcn_mfma_f32_16x16x32_bf16(pA, b1, acc1A, 0, 0, 0);
            accDA = __builtin_amdgcn_mfma_f32_16x16x32_bf16(pA, ones, accDA, 0, 0, 0);
            acc0B = __builtin_amdgcn_mfma_f32_16x16x32_bf16(pB, b0, acc0B, 0, 0, 0);
            acc1B = __builtin_amdgcn_mfma_f32_16x16x32_bf16(pB, b1, acc1B, 0, 0, 0);
            accDB = __builtin_amdgcn_mfma_f32_16x16x32_bf16(pB, ones, accDB, 0, 0, 0);
        }
        __builtin_amdgcn_s_barrier();
        __builtin_amdgcn_sched_barrier(0);
    }
#undef STAGE

    // epilogue: un-normalized numerators + denominators for both subtiles
    const int fcol = l & 15;
    const int pr = r * 2 + jh;
#pragma unroll
    for (int reg = 0; reg < 4; ++reg) {
        const int orow = (l >> 4) * 4 + reg;
        const long roA = (long)pr * (BB * NN) + (long)b * NN + i0 + w * 16 + orow;
        const long roB = roA + 64;
        num[roA * DD + h * HD + fcol]      = acc0A[reg];
        num[roA * DD + h * HD + 16 + fcol] = acc1A[reg];
        num[roB * DD + h * HD + fcol]      = acc0B[reg];
        num[roB * DD + h * HD + 16 + fcol] = acc1B[reg];
        if (fcol == 0) {
            den[roA * HH + h] = accDA[reg];
            den[roB * HH + h] = accDB[reg];
        }
    }
}

// ---------------------------------------------------------------------------
// Kernel 3: out = LayerNorm(H + mean_r (num_r / den_r)).  One wave per row.
// ---------------------------------------------------------------------------
__global__ __launch_bounds__(256) void finalize_kernel(
    const float* __restrict__ H, const float* __restrict__ num,
    const float* __restrict__ den,
    const float* __restrict__ gamma, const float* __restrict__ beta,
    float* __restrict__ out)
{
    const int w = threadIdx.x >> 6;
    const int l = threadIdx.x & 63;
    const long row = (long)blockIdx.x * 4 + w;    // over B*N rows
    const float2 hv = ((const float2*)(H + row * DD))[l];

    float ax = 0.f, ay = 0.f;
#pragma unroll
    for (int r = 0; r < RR; ++r) {
        float dsum = 0.f, nx = 0.f, ny = 0.f;
#pragma unroll
        for (int j = 0; j < 2; ++j) {
            const long ro = (long)(r * 2 + j) * (BB * NN) + row;
            dsum += den[ro * HH + (l >> 4)];
            const float2 nv = ((const float2*)(num + ro * DD))[l];
            nx += nv.x; ny += nv.y;
        }
        const float inv = (dsum > 0.f) ? 1.0f / dsum : 0.0f;
        ax = fmaf(nx, inv, ax);
        ay = fmaf(ny, inv, ay);
    }
    const float x0 = hv.x + ax * (1.0f / RR);
    const float x1 = hv.y + ay * (1.0f / RR);
    float s = x0 + x1, q = x0 * x0 + x1 * x1;
#pragma unroll
    for (int m = 1; m < 64; m <<= 1) {
        s += __shfl_xor(s, m);
        q += __shfl_xor(q, m);
    }
    const float mu  = s * (1.0f / DD);
    const float var = q * (1.0f / DD) - mu * mu;
    const float inv = rsqrtf(var + LN_EPS);
    const float g0 = gamma[l * 2], g1 = gamma[l * 2 + 1];
    const float b0 = beta[l * 2],  b1 = beta[l * 2 + 1];
    float2 o;
    o.x = (x0 - mu) * inv * g0 + b0;
    o.y = (x1 - mu) * inv * g1 + b1;
    ((float2*)(out + row * DD))[l] = o;
}

// ---------------------------------------------------------------------------
extern "C" void kernel_launch(void* const* d_in, const int* in_sizes, int n_in,
                              void* d_out, int out_size, void* d_ws, size_t ws_size,
                              hipStream_t stream)
{
    const float* H      = (const float*)d_in[0];
    const int*   A      = (const int*)d_in[1];
    const float* W      = (const float*)d_in[2];
    const float* a_src  = (const float*)d_in[3];
    const float* a_dst  = (const float*)d_in[4];
    const float* gamma  = (const float*)d_in[5];
    const float* beta   = (const float*)d_in[6];
    float* out = (float*)d_out;

    // workspace carve (~19.6 MB)
    char* ws = (char*)d_ws;
    float* num = (float*)ws;                     ws += (size_t)RR * 2 * BB * NN * DD * 4;  // 12.6 MB
    float* den = (float*)ws;                     ws += (size_t)RR * 2 * BB * NN * HH * 4;  // 393 KB
    float* es  = (float*)ws;                     ws += (size_t)RR * BB * HH * NN * 4;      // 196 KB
    float* ed  = (float*)ws;                     ws += (size_t)RR * BB * HH * NN * 4;      // 196 KB
    __hip_bfloat16* whT = (__hip_bfloat16*)ws;   ws += (size_t)RR * BB * HH * HD * NN * 2; // 3.15 MB
    unsigned* bmask = (unsigned*)ws;             ws += (size_t)RR * BB * NN * (NN / 32) * 4; // 3.15 MB

    prep_kernel<<<3840, 256, 0, stream>>>(H, A, W, a_src, a_dst, es, ed, whT, bmask);
    gat_attn_kernel<<<RR * BB * HH * 16 * 2, 256, 0, stream>>>(bmask, es, ed, whT, num, den);
    finalize_kernel<<<BB * NN / 4, 256, 0, stream>>>(H, num, den, gamma, beta, out);
}

// Round 9
// 87.523 us; speedup vs baseline: 1.3125x; 1.3125x over previous
//
#include <hip/hip_runtime.h>
#include <hip/hip_bf16.h>

// Problem constants (from reference setup_inputs)
#define RR 3
#define BB 2
#define NN 2048
#define DD 128
#define HH 4
#define HD 32
#define LEAKY 0.2f
#define LN_EPS 1e-5f
#define LOG2E 1.4426950408889634f

using f32x4  = __attribute__((ext_vector_type(4))) float;
using bf16x8 = __attribute__((ext_vector_type(8))) short;

__device__ __forceinline__ void gload_lds16(const void* g, void* l) {
    __builtin_amdgcn_global_load_lds(
        (const __attribute__((address_space(1))) unsigned*)g,
        (__attribute__((address_space(3))) unsigned*)l, 16, 0, 0);
}
__device__ __forceinline__ void gload_lds4(const void* g, void* l) {
    __builtin_amdgcn_global_load_lds(
        (const __attribute__((address_space(1))) unsigned*)g,
        (__attribute__((address_space(3))) unsigned*)l, 4, 0, 0);
}

// ---------------------------------------------------------------------------
// Kernel 0: compact A (int32 0/1, 100.7 MB) -> bitmask (3.1 MB).
// Pure streaming read; mandatory-input-BW floor (~17 us at 6 TB/s).
// grid = 3072 blocks, 256 threads. (Standalone: fusion experiments in R6/R7
// showed heterogeneous co-scheduling is strictly worse than the serial sum.)
// ---------------------------------------------------------------------------
__global__ __launch_bounds__(256) void compact_kernel(
    const int* __restrict__ A, unsigned* __restrict__ bm)
{
    const long g = (long)blockIdx.x * 256 + threadIdx.x;   // word index
    const int4* p = (const int4*)(A + g * 32);
    unsigned w = 0;
#pragma unroll
    for (int k = 0; k < 8; ++k) {
        int4 v = p[k];
        w |= (v.x != 0 ? 1u : 0u) << (k * 4 + 0);
        w |= (v.y != 0 ? 1u : 0u) << (k * 4 + 1);
        w |= (v.z != 0 ? 1u : 0u) << (k * 4 + 2);
        w |= (v.w != 0 ? 1u : 0u) << (k * 4 + 3);
    }
    bm[g] = w;
}

// ---------------------------------------------------------------------------
// Kernel 1: Wh = H @ W per (r,b,h); store Wh^T bf16 [rbh][f][n]; es/ed
// (log2e-scaled). LDS-staged H and W. grid = 768 blocks, 256 threads.
// ---------------------------------------------------------------------------
__global__ __launch_bounds__(256) void wh_kernel(
    const float* __restrict__ H, const float* __restrict__ W,
    const float* __restrict__ a_src, const float* __restrict__ a_dst,
    float* __restrict__ es, float* __restrict__ ed,
    __hip_bfloat16* __restrict__ whT)
{
    const int bid = blockIdx.x;
    const int nt = bid & 31;
    const int h  = (bid >> 5) & 3;
    const int b  = (bid >> 7) & 1;
    const int r  = bid >> 8;
    const int n0 = nt << 6;
    const int t  = threadIdx.x;

    __shared__ __align__(16) float Hs[64 * 128];
    __shared__ __align__(16) float Ws[128 * 32];

    const float* Hb = H + ((long)b * NN + n0) * DD;
#pragma unroll
    for (int k = 0; k < 8; ++k) {
        int f4 = t + 256 * k;
        ((float4*)Hs)[f4] = ((const float4*)Hb)[f4];
    }
    const float* Wb = W + (long)(r * HH + h) * DD * HD;
#pragma unroll
    for (int k = 0; k < 4; ++k) {
        int f4 = t + 256 * k;
        ((float4*)Ws)[f4] = ((const float4*)Wb)[f4];
    }
    __syncthreads();

    const int f  = t & 31;
    const int rg = t >> 5;
    const float av = a_src[(r * HH + h) * HD + f] * LOG2E;
    const float dv = a_dst[(r * HH + h) * HD + f] * LOG2E;
    const int rbh = (r * BB + b) * HH + h;

#pragma unroll
    for (int k = 0; k < 8; ++k) {
        const int row = rg * 8 + k;
        const float4* hrow = (const float4*)&Hs[row * 128];
        float acc = 0.0f;
#pragma unroll
        for (int d4 = 0; d4 < 32; ++d4) {
            float4 hv = hrow[d4];
            acc += hv.x * Ws[(d4 * 4 + 0) * 32 + f];
            acc += hv.y * Ws[(d4 * 4 + 1) * 32 + f];
            acc += hv.z * Ws[(d4 * 4 + 2) * 32 + f];
            acc += hv.w * Ws[(d4 * 4 + 3) * 32 + f];
        }
        whT[((long)rbh * HD + f) * NN + n0 + row] = __float2bfloat16(acc);
        float s = acc * av;
        float d = acc * dv;
#pragma unroll
        for (int m = 1; m < 32; m <<= 1) {
            s += __shfl_xor(s, m);
            d += __shfl_xor(d, m);
        }
        if (f == 0) {
            es[(long)rbh * NN + n0 + row] = s;
            ed[(long)rbh * NN + n0 + row] = d;
        }
    }
}

// ---------------------------------------------------------------------------
// Kernel 2: fused masked softmax + MFMA aggregation.
// block = (r,b,h, 128 i-rows, j-half of 1024). 4 waves; each wave owns TWO
// 16-row i-subtiles (rows w*16 and 64+w*16) -> every staged whT/ed byte is
// used twice. 8 double-buffered stages of 128 j via global_load_lds with
// per-wave counted vmcnt(5) and RAW s_barrier (no compiler vmcnt(0) drain).
// Row-max bound computed in-kernel from ed (any upper bound cancels exactly).
// grid = R*B*HH*16*2 = 768 blocks (XCD-chunk swizzled), 256 threads.
// ---------------------------------------------------------------------------
__global__ __launch_bounds__(256, 3) void gat_attn_kernel(
    const unsigned* __restrict__ bm, const float* __restrict__ es,
    const float* __restrict__ ed, const __hip_bfloat16* __restrict__ whT,
    float* __restrict__ num, float* __restrict__ den)
{
    // XCD-chunked bijective swizzle (768 % 8 == 0)
    const int lg = ((int)blockIdx.x % 8) * 96 + (int)blockIdx.x / 8;
    const int jh = lg & 1;
    const int it = (lg >> 1) & 15;         // 16 tiles of 128 rows
    const int h  = (lg >> 5) & 3;
    const int b  = (lg >> 7) & 1;
    const int r  = lg >> 8;
    const int i0 = it << 7;
    const int tid = threadIdx.x;
    const int w = tid >> 6;
    const int l = tid & 63;
    const int row = l & 15;                // A-frag row / B-frag f-col
    const int kg  = l >> 4;                // k-octet
    const int f31 = l & 31;
    const int kgr = l >> 5;

    __shared__ __align__(16) short    whs[2][4][4][32][8]; // [buf][jc][kg][f][8] : 16 KB
    __shared__ __align__(16) unsigned bms[2][4][128];      // [buf][jc][blockrow] : 4 KB
    __shared__ __align__(16) float    eds[2][4][32];       // [buf][jc][j]        : 1 KB
    __shared__ float red[4];

    const int rbh = (r * BB + b) * HH + h;
    const long rbNN = (long)(r * BB + b) * NN;
    const __hip_bfloat16* whTr = whT + (long)rbh * HD * NN;
    const float* edr = ed + (long)rbh * NN;
    const int jbase = jh * (NN / 2);

#define STAGE(s, nb) do {                                                           \
        const int j0s = jbase + (s) * 128;                                          \
        gload_lds16(whTr + (long)f31 * NN + j0s + w * 32 + kgr * 8,                 \
                    &whs[nb][w][0][0][0]);                                          \
        gload_lds16(whTr + (long)f31 * NN + j0s + w * 32 + (2 + kgr) * 8,           \
                    &whs[nb][w][2][0][0]);                                          \
        gload_lds4(bm + (rbNN + i0 + l) * (NN / 32) + (j0s >> 5) + w,               \
                   &bms[nb][w][0]);                                                 \
        gload_lds4(bm + (rbNN + i0 + 64 + l) * (NN / 32) + (j0s >> 5) + w,          \
                   &bms[nb][w][64]);                                                \
        if (l < 32) gload_lds4(edr + j0s + w * 32 + l, &eds[nb][w][0]);             \
    } while (0)

    STAGE(0, 0);   // issue first stage before the med reduce (latency overlap)

    // block-wide max of ed over all 2048 j (upper bound; cancels in num/den)
    float4 m0 = ((const float4*)edr)[tid * 2];
    float4 m1 = ((const float4*)edr)[tid * 2 + 1];
    float mm = fmaxf(fmaxf(fmaxf(m0.x, m0.y), fmaxf(m0.z, m0.w)),
                     fmaxf(fmaxf(m1.x, m1.y), fmaxf(m1.z, m1.w)));
#pragma unroll
    for (int d = 1; d < 64; d <<= 1) mm = fmaxf(mm, __shfl_xor(mm, d));
    if (l == 0) red[w] = mm;
    __syncthreads();
    const float medf = fmaxf(fmaxf(red[0], red[1]), fmaxf(red[2], red[3]));

    // per-row softmax constants for the two subtiles (log2e-scaled domain)
    const float esvA = es[(long)rbh * NN + i0 + w * 16 + row];
    const float esvB = es[(long)rbh * NN + i0 + 64 + w * 16 + row];
    const float xA = esvA + medf, xB = esvB + medf;
    const float MA = fmaxf(xA, LEAKY * xA), MB = fmaxf(xB, LEAKY * xB);
    const float uA = esvA - MA, vA = fmaf(LEAKY, esvA, -MA);
    const float uB = esvB - MB, vB = fmaf(LEAKY, esvB, -MB);

    f32x4 acc0A = {0,0,0,0}, acc1A = {0,0,0,0}, accDA = {0,0,0,0};
    f32x4 acc0B = {0,0,0,0}, acc1B = {0,0,0,0}, accDB = {0,0,0,0};
    bf16x8 ones;
#pragma unroll
    for (int i = 0; i < 8; ++i) ones[i] = (short)0x3F80;   // bf16 1.0

    for (int s = 0; s < 8; ++s) {
        const int cb = s & 1, nb = cb ^ 1;
        if (s < 7) {
            STAGE(s + 1, nb);
            asm volatile("s_waitcnt vmcnt(5)" ::: "memory");
        } else {
            asm volatile("s_waitcnt vmcnt(0)" ::: "memory");
        }
        __builtin_amdgcn_s_barrier();
        __builtin_amdgcn_sched_barrier(0);

#pragma unroll
        for (int jc = 0; jc < 4; ++jc) {
            bf16x8 b0 = *(const bf16x8*)&whs[cb][jc][kg][row][0];
            bf16x8 b1 = *(const bf16x8*)&whs[cb][jc][kg][row + 16][0];
            float4 e0 = *(const float4*)&eds[cb][jc][kg * 8];
            float4 e1 = *(const float4*)&eds[cb][jc][kg * 8 + 4];
            const unsigned mybA = (bms[cb][jc][w * 16 + row] >> (kg * 8)) & 0xffu;
            const unsigned mybB = (bms[cb][jc][64 + w * 16 + row] >> (kg * 8)) & 0xffu;

            float ev[8];
            ev[0] = e0.x; ev[1] = e0.y; ev[2] = e0.z; ev[3] = e0.w;
            ev[4] = e1.x; ev[5] = e1.y; ev[6] = e1.z; ev[7] = e1.w;

            bf16x8 pA, pB;
#pragma unroll
            for (int c = 0; c < 8; ++c) {
                float pa = __builtin_amdgcn_exp2f(
                    fmaxf(uA + ev[c], fmaf(LEAKY, ev[c], vA)));
                float pb = __builtin_amdgcn_exp2f(
                    fmaxf(uB + ev[c], fmaf(LEAKY, ev[c], vB)));
                const int ma = ((int)(mybA << (31 - c))) >> 31;   // v_bfe_i32
                const int mb = ((int)(mybB << (31 - c))) >> 31;
                pa = __uint_as_float(__float_as_uint(pa) & (unsigned)ma);
                pb = __uint_as_float(__float_as_uint(pb) & (unsigned)mb);
                __hip_bfloat16 ha = __float2bfloat16(pa);
                __hip_bfloat16 hb = __float2bfloat16(pb);
                pA[c] = __builtin_bit_cast(short, ha);
                pB[c] = __builtin_bit_cast(short, hb);
            }

            acc0A = __builtin_amdgcn_mfma_f32_16x16x32_bf16(pA, b0, acc0A, 0, 0, 0);
            acc1A = __builtin_amdgcn_mfma_f32_16x16x32_bf16(pA, b1, acc1A, 0, 0, 0);
            accDA = __builtin_amdgcn_mfma_f32_16x16x32_bf16(pA, ones, accDA, 0, 0, 0);
            acc0B = __builtin_amdgcn_mfma_f32_16x16x32_bf16(pB, b0, acc0B, 0, 0, 0);
            acc1B = __builtin_amdgcn_mfma_f32_16x16x32_bf16(pB, b1, acc1B, 0, 0, 0);
            accDB = __builtin_amdgcn_mfma_f32_16x16x32_bf16(pB, ones, accDB, 0, 0, 0);
        }
        __builtin_amdgcn_s_barrier();
        __builtin_amdgcn_sched_barrier(0);
    }
#undef STAGE

    // epilogue: un-normalized numerators + denominators for both subtiles
    const int fcol = l & 15;
    const int pr = r * 2 + jh;
#pragma unroll
    for (int reg = 0; reg < 4; ++reg) {
        const int orow = (l >> 4) * 4 + reg;
        const long roA = (long)pr * (BB * NN) + (long)b * NN + i0 + w * 16 + orow;
        const long roB = roA + 64;
        num[roA * DD + h * HD + fcol]      = acc0A[reg];
        num[roA * DD + h * HD + 16 + fcol] = acc1A[reg];
        num[roB * DD + h * HD + fcol]      = acc0B[reg];
        num[roB * DD + h * HD + 16 + fcol] = acc1B[reg];
        if (fcol == 0) {
            den[roA * HH + h] = accDA[reg];
            den[roB * HH + h] = accDB[reg];
        }
    }
}

// ---------------------------------------------------------------------------
// Kernel 3: out = LayerNorm(H + mean_r (num_r / den_r)).  One wave per row.
// ---------------------------------------------------------------------------
__global__ __launch_bounds__(256) void finalize_kernel(
    const float* __restrict__ H, const float* __restrict__ num,
    const float* __restrict__ den,
    const float* __restrict__ gamma, const float* __restrict__ beta,
    float* __restrict__ out)
{
    const int w = threadIdx.x >> 6;
    const int l = threadIdx.x & 63;
    const long row = (long)blockIdx.x * 4 + w;    // over B*N rows
    const float2 hv = ((const float2*)(H + row * DD))[l];

    float ax = 0.f, ay = 0.f;
#pragma unroll
    for (int r = 0; r < RR; ++r) {
        float dsum = 0.f, nx = 0.f, ny = 0.f;
#pragma unroll
        for (int j = 0; j < 2; ++j) {
            const long ro = (long)(r * 2 + j) * (BB * NN) + row;
            dsum += den[ro * HH + (l >> 4)];
            const float2 nv = ((const float2*)(num + ro * DD))[l];
            nx += nv.x; ny += nv.y;
        }
        const float inv = (dsum > 0.f) ? 1.0f / dsum : 0.0f;
        ax = fmaf(nx, inv, ax);
        ay = fmaf(ny, inv, ay);
    }
    const float x0 = hv.x + ax * (1.0f / RR);
    const float x1 = hv.y + ay * (1.0f / RR);
    float s = x0 + x1, q = x0 * x0 + x1 * x1;
#pragma unroll
    for (int m = 1; m < 64; m <<= 1) {
        s += __shfl_xor(s, m);
        q += __shfl_xor(q, m);
    }
    const float mu  = s * (1.0f / DD);
    const float var = q * (1.0f / DD) - mu * mu;
    const float inv = rsqrtf(var + LN_EPS);
    const float g0 = gamma[l * 2], g1 = gamma[l * 2 + 1];
    const float b0 = beta[l * 2],  b1 = beta[l * 2 + 1];
    float2 o;
    o.x = (x0 - mu) * inv * g0 + b0;
    o.y = (x1 - mu) * inv * g1 + b1;
    ((float2*)(out + row * DD))[l] = o;
}

// ---------------------------------------------------------------------------
extern "C" void kernel_launch(void* const* d_in, const int* in_sizes, int n_in,
                              void* d_out, int out_size, void* d_ws, size_t ws_size,
                              hipStream_t stream)
{
    const float* H      = (const float*)d_in[0];
    const int*   A      = (const int*)d_in[1];
    const float* W      = (const float*)d_in[2];
    const float* a_src  = (const float*)d_in[3];
    const float* a_dst  = (const float*)d_in[4];
    const float* gamma  = (const float*)d_in[5];
    const float* beta   = (const float*)d_in[6];
    float* out = (float*)d_out;

    // workspace carve (~19.6 MB)
    char* ws = (char*)d_ws;
    float* num = (float*)ws;                     ws += (size_t)RR * 2 * BB * NN * DD * 4;  // 12.6 MB
    float* den = (float*)ws;                     ws += (size_t)RR * 2 * BB * NN * HH * 4;  // 393 KB
    float* es  = (float*)ws;                     ws += (size_t)RR * BB * HH * NN * 4;      // 196 KB
    float* ed  = (float*)ws;                     ws += (size_t)RR * BB * HH * NN * 4;      // 196 KB
    __hip_bfloat16* whT = (__hip_bfloat16*)ws;   ws += (size_t)RR * BB * HH * HD * NN * 2; // 3.15 MB
    unsigned* bmask = (unsigned*)ws;             ws += (size_t)RR * BB * NN * (NN / 32) * 4; // 3.15 MB

    compact_kernel<<<RR * BB * NN * (NN / 32) / 256, 256, 0, stream>>>(A, bmask);
    wh_kernel<<<RR * BB * HH * (NN / 64), 256, 0, stream>>>(H, W, a_src, a_dst, es, ed, whT);
    gat_attn_kernel<<<RR * BB * HH * 16 * 2, 256, 0, stream>>>(bmask, es, ed, whT, num, den);
    finalize_kernel<<<BB * NN / 4, 256, 0, stream>>>(H, num, den, gamma, beta, out);
}

// Round 10
// 73.503 us; speedup vs baseline: 1.5629x; 1.1908x over previous
//
#include <hip/hip_runtime.h>
#include <hip/hip_bf16.h>

// Problem constants (from reference setup_inputs)
#define RR 3
#define BB 2
#define NN 2048
#define DD 128
#define HH 4
#define HD 32
#define LEAKY 0.2f
#define LN_EPS 1e-5f
#define LOG2E 1.4426950408889634f

using f32x4  = __attribute__((ext_vector_type(4))) float;
using bf16x8 = __attribute__((ext_vector_type(8))) short;

__device__ __forceinline__ void gload_lds16(const void* g, void* l) {
    __builtin_amdgcn_global_load_lds(
        (const __attribute__((address_space(1))) unsigned*)g,
        (__attribute__((address_space(3))) unsigned*)l, 16, 0, 0);
}
__device__ __forceinline__ void gload_lds4(const void* g, void* l) {
    __builtin_amdgcn_global_load_lds(
        (const __attribute__((address_space(1))) unsigned*)g,
        (__attribute__((address_space(3))) unsigned*)l, 4, 0, 0);
}

// ---------------------------------------------------------------------------
// Kernel 0: compact A -> bitmask via ballot (coalesced dword loads; the
// v_cmp IS the bit-pack), plus 16 leading blocks casting H -> bf16 Hb.
// Each wave: 2048 consecutive ints -> 32 ballots -> 64 coalesced word writes.
// grid = 16 + 3072 blocks, 256 threads.
// ---------------------------------------------------------------------------
__global__ __launch_bounds__(256) void compact_kernel(
    const int* __restrict__ A, unsigned* __restrict__ bm,
    const float* __restrict__ H, __hip_bfloat16* __restrict__ Hb)
{
    const int bid = blockIdx.x;
    if (bid < 16) {
        // cast role: one row of H (128 fp32) per thread -> bf16
        const int row = bid * 256 + threadIdx.x;        // 0..4095 = B*N
        const float4* src = (const float4*)(H + (long)row * DD);
        ushort4* dst = (ushort4*)(Hb + (long)row * DD);
#pragma unroll
        for (int k = 0; k < 32; ++k) {
            float4 v = src[k];
            ushort4 o;
            o.x = __builtin_bit_cast(unsigned short, __float2bfloat16(v.x));
            o.y = __builtin_bit_cast(unsigned short, __float2bfloat16(v.y));
            o.z = __builtin_bit_cast(unsigned short, __float2bfloat16(v.z));
            o.w = __builtin_bit_cast(unsigned short, __float2bfloat16(v.w));
            dst[k] = o;
        }
        return;
    }
    const int cb = bid - 16;                            // 0..3071
    const int wave = cb * 4 + ((int)threadIdx.x >> 6);
    const int lane = threadIdx.x & 63;
    const long base = (long)wave * 2048;
    const int* Ap = A + base;
    unsigned word = 0;
#pragma unroll
    for (int e = 0; e < 32; ++e) {
        const int v = Ap[e * 64 + lane];                // wave: 256B contiguous
        const unsigned long long bal = __ballot(v != 0);
        if ((lane >> 1) == e)
            word = (lane & 1) ? (unsigned)(bal >> 32) : (unsigned)bal;
    }
    bm[(base >> 5) + lane] = word;                      // 64 words, coalesced
}

// ---------------------------------------------------------------------------
// Kernel 1: Wh^T = W^T @ H^T per (r,b,h) via bf16 MFMA (402 MFLOP total).
// A-frag = W^T (lane: row f=l&15, k-octet l>>4 — same convention as gat's P),
// B-frag = H row bf16x8 (col n=l&15), C: col=l&15=n, row=(l>>4)*4+reg=f.
// es/ed computed from the fp32 accumulators + 2 cross-lane reduces.
// grid = 24 rbh * 16 n-chunks = 384 blocks, 256 threads (4 waves * 32 n).
// ---------------------------------------------------------------------------
__global__ __launch_bounds__(256) void wh_kernel(
    const __hip_bfloat16* __restrict__ Hb, const float* __restrict__ W,
    const float* __restrict__ a_src, const float* __restrict__ a_dst,
    float* __restrict__ es, float* __restrict__ ed,
    __hip_bfloat16* __restrict__ whT)
{
    const int bid = blockIdx.x;
    const int rbh = bid >> 4;          // (r*BB+b)*HH+h
    const int nch = bid & 15;          // 128-col chunk
    const int h = rbh & 3;
    const int b = (rbh >> 2) & 1;
    const int r = rbh >> 3;
    const int wi = r * HH + h;
    const int w  = threadIdx.x >> 6;
    const int l  = threadIdx.x & 63;
    const int lr = l & 15;             // in-tile row/col index
    const int lg = l >> 4;             // octet group

    // A-fragments (one-time): afr[mt][kt][e] = W[kt*32+lg*8+e][mt*16+lr]
    const float* Wp = W + (long)wi * DD * HD;
    bf16x8 afr[2][4];
#pragma unroll
    for (int mt = 0; mt < 2; ++mt)
#pragma unroll
        for (int kt = 0; kt < 4; ++kt)
#pragma unroll
            for (int e = 0; e < 8; ++e) {
                const float wv = Wp[(kt * 32 + lg * 8 + e) * HD + mt * 16 + lr];
                afr[mt][kt][e] = __builtin_bit_cast(short, __float2bfloat16(wv));
            }

    // a-vec entries for this lane's 8 f-rows (log2e pre-scaled)
    float av[2][4], dv[2][4];
#pragma unroll
    for (int mt = 0; mt < 2; ++mt)
#pragma unroll
        for (int reg = 0; reg < 4; ++reg) {
            const int f = mt * 16 + lg * 4 + reg;
            av[mt][reg] = a_src[wi * HD + f] * LOG2E;
            dv[mt][reg] = a_dst[wi * HD + f] * LOG2E;
        }

#pragma unroll
    for (int nt = 0; nt < 2; ++nt) {
        const int ncol = nch * 128 + w * 32 + nt * 16 + lr;
        const __hip_bfloat16* hrow = Hb + ((long)b * NN + ncol) * DD;
        f32x4 acc0 = {0.f, 0.f, 0.f, 0.f};
        f32x4 acc1 = {0.f, 0.f, 0.f, 0.f};
#pragma unroll
        for (int kt = 0; kt < 4; ++kt) {
            bf16x8 bfr = *(const bf16x8*)(hrow + kt * 32 + lg * 8);
            acc0 = __builtin_amdgcn_mfma_f32_16x16x32_bf16(afr[0][kt], bfr, acc0, 0, 0, 0);
            acc1 = __builtin_amdgcn_mfma_f32_16x16x32_bf16(afr[1][kt], bfr, acc1, 0, 0, 0);
        }
        float s = 0.f, d = 0.f;
#pragma unroll
        for (int reg = 0; reg < 4; ++reg) {
            const int f0 = lg * 4 + reg;
            const int f1 = 16 + lg * 4 + reg;
            whT[((long)rbh * HD + f0) * NN + ncol] = __float2bfloat16(acc0[reg]);
            whT[((long)rbh * HD + f1) * NN + ncol] = __float2bfloat16(acc1[reg]);
            s = fmaf(acc0[reg], av[0][reg], s);
            s = fmaf(acc1[reg], av[1][reg], s);
            d = fmaf(acc0[reg], dv[0][reg], d);
            d = fmaf(acc1[reg], dv[1][reg], d);
        }
        s += __shfl_xor(s, 16); s += __shfl_xor(s, 32);
        d += __shfl_xor(d, 16); d += __shfl_xor(d, 32);
        if (l < 16) {
            es[(long)rbh * NN + ncol] = s;
            ed[(long)rbh * NN + ncol] = d;
        }
    }
}

// ---------------------------------------------------------------------------
// Kernel 2: fused masked softmax + MFMA aggregation (unchanged from R8 —
// proven ~14 us). 128 i-rows x j-half per block, double-buffered
// global_load_lds staging, counted vmcnt(5), raw s_barrier.
// ---------------------------------------------------------------------------
__global__ __launch_bounds__(256, 3) void gat_attn_kernel(
    const unsigned* __restrict__ bm, const float* __restrict__ es,
    const float* __restrict__ ed, const __hip_bfloat16* __restrict__ whT,
    float* __restrict__ num, float* __restrict__ den)
{
    // XCD-chunked bijective swizzle (768 % 8 == 0)
    const int lg = ((int)blockIdx.x % 8) * 96 + (int)blockIdx.x / 8;
    const int jh = lg & 1;
    const int it = (lg >> 1) & 15;
    const int h  = (lg >> 5) & 3;
    const int b  = (lg >> 7) & 1;
    const int r  = lg >> 8;
    const int i0 = it << 7;
    const int tid = threadIdx.x;
    const int w = tid >> 6;
    const int l = tid & 63;
    const int row = l & 15;
    const int kg  = l >> 4;
    const int f31 = l & 31;
    const int kgr = l >> 5;

    __shared__ __align__(16) short    whs[2][4][4][32][8];
    __shared__ __align__(16) unsigned bms[2][4][128];
    __shared__ __align__(16) float    eds[2][4][32];
    __shared__ float red[4];

    const int rbh = (r * BB + b) * HH + h;
    const long rbNN = (long)(r * BB + b) * NN;
    const __hip_bfloat16* whTr = whT + (long)rbh * HD * NN;
    const float* edr = ed + (long)rbh * NN;
    const int jbase = jh * (NN / 2);

#define STAGE(s, nb) do {                                                           \
        const int j0s = jbase + (s) * 128;                                          \
        gload_lds16(whTr + (long)f31 * NN + j0s + w * 32 + kgr * 8,                 \
                    &whs[nb][w][0][0][0]);                                          \
        gload_lds16(whTr + (long)f31 * NN + j0s + w * 32 + (2 + kgr) * 8,           \
                    &whs[nb][w][2][0][0]);                                          \
        gload_lds4(bm + (rbNN + i0 + l) * (NN / 32) + (j0s >> 5) + w,               \
                   &bms[nb][w][0]);                                                 \
        gload_lds4(bm + (rbNN + i0 + 64 + l) * (NN / 32) + (j0s >> 5) + w,          \
                   &bms[nb][w][64]);                                                \
        if (l < 32) gload_lds4(edr + j0s + w * 32 + l, &eds[nb][w][0]);             \
    } while (0)

    STAGE(0, 0);

    // block-wide max of ed (upper bound; cancels exactly in num/den)
    float4 m0 = ((const float4*)edr)[tid * 2];
    float4 m1 = ((const float4*)edr)[tid * 2 + 1];
    float mm = fmaxf(fmaxf(fmaxf(m0.x, m0.y), fmaxf(m0.z, m0.w)),
                     fmaxf(fmaxf(m1.x, m1.y), fmaxf(m1.z, m1.w)));
#pragma unroll
    for (int d = 1; d < 64; d <<= 1) mm = fmaxf(mm, __shfl_xor(mm, d));
    if (l == 0) red[w] = mm;
    __syncthreads();
    const float medf = fmaxf(fmaxf(red[0], red[1]), fmaxf(red[2], red[3]));

    const float esvA = es[(long)rbh * NN + i0 + w * 16 + row];
    const float esvB = es[(long)rbh * NN + i0 + 64 + w * 16 + row];
    const float xA = esvA + medf, xB = esvB + medf;
    const float MA = fmaxf(xA, LEAKY * xA), MB = fmaxf(xB, LEAKY * xB);
    const float uA = esvA - MA, vA = fmaf(LEAKY, esvA, -MA);
    const float uB = esvB - MB, vB = fmaf(LEAKY, esvB, -MB);

    f32x4 acc0A = {0,0,0,0}, acc1A = {0,0,0,0}, accDA = {0,0,0,0};
    f32x4 acc0B = {0,0,0,0}, acc1B = {0,0,0,0}, accDB = {0,0,0,0};
    bf16x8 ones;
#pragma unroll
    for (int i = 0; i < 8; ++i) ones[i] = (short)0x3F80;

    for (int s = 0; s < 8; ++s) {
        const int cb = s & 1, nb = cb ^ 1;
        if (s < 7) {
            STAGE(s + 1, nb);
            asm volatile("s_waitcnt vmcnt(5)" ::: "memory");
        } else {
            asm volatile("s_waitcnt vmcnt(0)" ::: "memory");
        }
        __builtin_amdgcn_s_barrier();
        __builtin_amdgcn_sched_barrier(0);

#pragma unroll
        for (int jc = 0; jc < 4; ++jc) {
            bf16x8 b0 = *(const bf16x8*)&whs[cb][jc][kg][row][0];
            bf16x8 b1 = *(const bf16x8*)&whs[cb][jc][kg][row + 16][0];
            float4 e0 = *(const float4*)&eds[cb][jc][kg * 8];
            float4 e1 = *(const float4*)&eds[cb][jc][kg * 8 + 4];
            const unsigned mybA = (bms[cb][jc][w * 16 + row] >> (kg * 8)) & 0xffu;
            const unsigned mybB = (bms[cb][jc][64 + w * 16 + row] >> (kg * 8)) & 0xffu;

            float ev[8];
            ev[0] = e0.x; ev[1] = e0.y; ev[2] = e0.z; ev[3] = e0.w;
            ev[4] = e1.x; ev[5] = e1.y; ev[6] = e1.z; ev[7] = e1.w;

            bf16x8 pA, pB;
#pragma unroll
            for (int c = 0; c < 8; ++c) {
                float pa = __builtin_amdgcn_exp2f(
                    fmaxf(uA + ev[c], fmaf(LEAKY, ev[c], vA)));
                float pb = __builtin_amdgcn_exp2f(
                    fmaxf(uB + ev[c], fmaf(LEAKY, ev[c], vB)));
                const int ma = ((int)(mybA << (31 - c))) >> 31;
                const int mb = ((int)(mybB << (31 - c))) >> 31;
                pa = __uint_as_float(__float_as_uint(pa) & (unsigned)ma);
                pb = __uint_as_float(__float_as_uint(pb) & (unsigned)mb);
                __hip_bfloat16 ha = __float2bfloat16(pa);
                __hip_bfloat16 hb = __float2bfloat16(pb);
                pA[c] = __builtin_bit_cast(short, ha);
                pB[c] = __builtin_bit_cast(short, hb);
            }

            acc0A = __builtin_amdgcn_mfma_f32_16x16x32_bf16(pA, b0, acc0A, 0, 0, 0);
            acc1A = __builtin_amdgcn_mfma_f32_16x16x32_bf16(pA, b1, acc1A, 0, 0, 0);
            accDA = __builtin_amdgcn_mfma_f32_16x16x32_bf16(pA, ones, accDA, 0, 0, 0);
            acc0B = __builtin_amdgcn_mfma_f32_16x16x32_bf16(pB, b0, acc0B, 0, 0, 0);
            acc1B = __builtin_amdgcn_mfma_f32_16x16x32_bf16(pB, b1, acc1B, 0, 0, 0);
            accDB = __builtin_amdgcn_mfma_f32_16x16x32_bf16(pB, ones, accDB, 0, 0, 0);
        }
        __builtin_amdgcn_s_barrier();
        __builtin_amdgcn_sched_barrier(0);
    }
#undef STAGE

    const int fcol = l & 15;
    const int pr = r * 2 + jh;
#pragma unroll
    for (int reg = 0; reg < 4; ++reg) {
        const int orow = (l >> 4) * 4 + reg;
        const long roA = (long)pr * (BB * NN) + (long)b * NN + i0 + w * 16 + orow;
        const long roB = roA + 64;
        num[roA * DD + h * HD + fcol]      = acc0A[reg];
        num[roA * DD + h * HD + 16 + fcol] = acc1A[reg];
        num[roB * DD + h * HD + fcol]      = acc0B[reg];
        num[roB * DD + h * HD + 16 + fcol] = acc1B[reg];
        if (fcol == 0) {
            den[roA * HH + h] = accDA[reg];
            den[roB * HH + h] = accDB[reg];
        }
    }
}

// ---------------------------------------------------------------------------
// Kernel 3: out = LayerNorm(H + mean_r (num_r / den_r)).  One wave per row.
// ---------------------------------------------------------------------------
__global__ __launch_bounds__(256) void finalize_kernel(
    const float* __restrict__ H, const float* __restrict__ num,
    const float* __restrict__ den,
    const float* __restrict__ gamma, const float* __restrict__ beta,
    float* __restrict__ out)
{
    const int w = threadIdx.x >> 6;
    const int l = threadIdx.x & 63;
    const long row = (long)blockIdx.x * 4 + w;
    const float2 hv = ((const float2*)(H + row * DD))[l];

    float ax = 0.f, ay = 0.f;
#pragma unroll
    for (int r = 0; r < RR; ++r) {
        float dsum = 0.f, nx = 0.f, ny = 0.f;
#pragma unroll
        for (int j = 0; j < 2; ++j) {
            const long ro = (long)(r * 2 + j) * (BB * NN) + row;
            dsum += den[ro * HH + (l >> 4)];
            const float2 nv = ((const float2*)(num + ro * DD))[l];
            nx += nv.x; ny += nv.y;
        }
        const float inv = (dsum > 0.f) ? 1.0f / dsum : 0.0f;
        ax = fmaf(nx, inv, ax);
        ay = fmaf(ny, inv, ay);
    }
    const float x0 = hv.x + ax * (1.0f / RR);
    const float x1 = hv.y + ay * (1.0f / RR);
    float s = x0 + x1, q = x0 * x0 + x1 * x1;
#pragma unroll
    for (int m = 1; m < 64; m <<= 1) {
        s += __shfl_xor(s, m);
        q += __shfl_xor(q, m);
    }
    const float mu  = s * (1.0f / DD);
    const float var = q * (1.0f / DD) - mu * mu;
    const float inv = rsqrtf(var + LN_EPS);
    const float g0 = gamma[l * 2], g1 = gamma[l * 2 + 1];
    const float b0 = beta[l * 2],  b1 = beta[l * 2 + 1];
    float2 o;
    o.x = (x0 - mu) * inv * g0 + b0;
    o.y = (x1 - mu) * inv * g1 + b1;
    ((float2*)(out + row * DD))[l] = o;
}

// ---------------------------------------------------------------------------
extern "C" void kernel_launch(void* const* d_in, const int* in_sizes, int n_in,
                              void* d_out, int out_size, void* d_ws, size_t ws_size,
                              hipStream_t stream)
{
    const float* H      = (const float*)d_in[0];
    const int*   A      = (const int*)d_in[1];
    const float* W      = (const float*)d_in[2];
    const float* a_src  = (const float*)d_in[3];
    const float* a_dst  = (const float*)d_in[4];
    const float* gamma  = (const float*)d_in[5];
    const float* beta   = (const float*)d_in[6];
    float* out = (float*)d_out;

    // workspace carve (~20.7 MB)
    char* ws = (char*)d_ws;
    float* num = (float*)ws;                     ws += (size_t)RR * 2 * BB * NN * DD * 4;  // 12.6 MB
    float* den = (float*)ws;                     ws += (size_t)RR * 2 * BB * NN * HH * 4;  // 393 KB
    float* es  = (float*)ws;                     ws += (size_t)RR * BB * HH * NN * 4;      // 196 KB
    float* ed  = (float*)ws;                     ws += (size_t)RR * BB * HH * NN * 4;      // 196 KB
    __hip_bfloat16* whT = (__hip_bfloat16*)ws;   ws += (size_t)RR * BB * HH * HD * NN * 2; // 3.15 MB
    unsigned* bmask = (unsigned*)ws;             ws += (size_t)RR * BB * NN * (NN / 32) * 4; // 3.15 MB
    __hip_bfloat16* Hb = (__hip_bfloat16*)ws;    ws += (size_t)BB * NN * DD * 2;           // 1.05 MB

    compact_kernel<<<16 + RR * BB * NN * (NN / 32) / 256, 256, 0, stream>>>(A, bmask, H, Hb);
    wh_kernel<<<24 * 16, 256, 0, stream>>>(Hb, W, a_src, a_dst, es, ed, whT);
    gat_attn_kernel<<<RR * BB * HH * 16 * 2, 256, 0, stream>>>(bmask, es, ed, whT, num, den);
    finalize_kernel<<<BB * NN / 4, 256, 0, stream>>>(H, num, den, gamma, beta, out);
}

// Round 11
// 64.554 us; speedup vs baseline: 1.7796x; 1.1386x over previous
//
#include <hip/hip_runtime.h>
#include <hip/hip_bf16.h>

// Problem constants (from reference setup_inputs)
#define RR 3
#define BB 2
#define NN 2048
#define DD 128
#define HH 4
#define HD 32
#define LEAKY 0.2f
#define LN_EPS 1e-5f
#define LOG2E 1.4426950408889634f

using f32x4  = __attribute__((ext_vector_type(4))) float;
using bf16x8 = __attribute__((ext_vector_type(8))) short;

__device__ __forceinline__ void gload_lds16(const void* g, void* l) {
    __builtin_amdgcn_global_load_lds(
        (const __attribute__((address_space(1))) unsigned*)g,
        (__attribute__((address_space(3))) unsigned*)l, 16, 0, 0);
}
__device__ __forceinline__ void gload_lds4(const void* g, void* l) {
    __builtin_amdgcn_global_load_lds(
        (const __attribute__((address_space(1))) unsigned*)g,
        (__attribute__((address_space(3))) unsigned*)l, 4, 0, 0);
}
__device__ __forceinline__ unsigned short bfb(float x) {
    return __builtin_bit_cast(unsigned short, __float2bfloat16(x));
}

// ---------------------------------------------------------------------------
// Kernel 1: fused prep. grid = 384 + 3072 blocks, 256 threads, NO LDS.
//  - bid<384: wh role. Wh^T = W^T@H^T per (r,b,h) via bf16 MFMA; H loaded
//    fp32 + converted in-register (same RNE rounding as a pre-cast pass).
//    Writes whT bf16 [rbh][f][n] and es/ed (log2e-scaled).
//  - bid>=384: ballot compact role. A -> bitmask; lane-coalesced dword
//    loads, v_cmp IS the bit-pack (ballot), 64 coalesced word writes/wave.
// No dependency between roles; wh (~3us) hides under the A stream (~18us).
// ---------------------------------------------------------------------------
__global__ __launch_bounds__(256) void prep_kernel(
    const float* __restrict__ H, const int* __restrict__ A,
    const float* __restrict__ W,
    const float* __restrict__ a_src, const float* __restrict__ a_dst,
    float* __restrict__ es, float* __restrict__ ed,
    __hip_bfloat16* __restrict__ whT, unsigned* __restrict__ bm)
{
    const int bid = blockIdx.x;
    const int t = threadIdx.x;

    if (bid >= 384) {
        // ---- ballot compact role ----
        const int cb = bid - 384;
        const int wave = cb * 4 + (t >> 6);
        const int lane = t & 63;
        const long base = (long)wave * 2048;
        const int* Ap = A + base;
        unsigned word = 0;
#pragma unroll
        for (int e = 0; e < 32; ++e) {
            const int v = Ap[e * 64 + lane];            // wave: 256B contiguous
            const unsigned long long bal = __ballot(v != 0);
            if ((lane >> 1) == e)
                word = (lane & 1) ? (unsigned)(bal >> 32) : (unsigned)bal;
        }
        bm[(base >> 5) + lane] = word;                  // 64 words, coalesced
        return;
    }

    // ---- wh role ----
    const int rbh = bid >> 4;          // (r*BB+b)*HH+h
    const int nch = bid & 15;          // 128-col chunk
    const int h = rbh & 3;
    const int b = (rbh >> 2) & 1;
    const int r = rbh >> 3;
    const int wi = r * HH + h;
    const int w  = t >> 6;
    const int l  = t & 63;
    const int lr = l & 15;
    const int lg = l >> 4;

    // A-fragments: afr[mt][kt][e] = W[kt*32+lg*8+e][mt*16+lr]  (bf16)
    const float* Wp = W + (long)wi * DD * HD;
    bf16x8 afr[2][4];
#pragma unroll
    for (int mt = 0; mt < 2; ++mt)
#pragma unroll
        for (int kt = 0; kt < 4; ++kt)
#pragma unroll
            for (int e = 0; e < 8; ++e)
                afr[mt][kt][e] = (short)bfb(Wp[(kt * 32 + lg * 8 + e) * HD + mt * 16 + lr]);

    float av[2][4], dv[2][4];
#pragma unroll
    for (int mt = 0; mt < 2; ++mt)
#pragma unroll
        for (int reg = 0; reg < 4; ++reg) {
            const int f = mt * 16 + lg * 4 + reg;
            av[mt][reg] = a_src[wi * HD + f] * LOG2E;
            dv[mt][reg] = a_dst[wi * HD + f] * LOG2E;
        }

#pragma unroll
    for (int nt = 0; nt < 2; ++nt) {
        const int ncol = nch * 128 + w * 32 + nt * 16 + lr;
        const float4* hrow4 = (const float4*)(H + ((long)b * NN + ncol) * DD);
        f32x4 acc0 = {0.f, 0.f, 0.f, 0.f};
        f32x4 acc1 = {0.f, 0.f, 0.f, 0.f};
#pragma unroll
        for (int kt = 0; kt < 4; ++kt) {
            float4 h0 = hrow4[kt * 8 + lg * 2];
            float4 h1 = hrow4[kt * 8 + lg * 2 + 1];
            bf16x8 bfr;
            bfr[0] = (short)bfb(h0.x); bfr[1] = (short)bfb(h0.y);
            bfr[2] = (short)bfb(h0.z); bfr[3] = (short)bfb(h0.w);
            bfr[4] = (short)bfb(h1.x); bfr[5] = (short)bfb(h1.y);
            bfr[6] = (short)bfb(h1.z); bfr[7] = (short)bfb(h1.w);
            acc0 = __builtin_amdgcn_mfma_f32_16x16x32_bf16(afr[0][kt], bfr, acc0, 0, 0, 0);
            acc1 = __builtin_amdgcn_mfma_f32_16x16x32_bf16(afr[1][kt], bfr, acc1, 0, 0, 0);
        }
        float s = 0.f, d = 0.f;
#pragma unroll
        for (int reg = 0; reg < 4; ++reg) {
            const int f0 = lg * 4 + reg;
            const int f1 = 16 + lg * 4 + reg;
            whT[((long)rbh * HD + f0) * NN + ncol] = __float2bfloat16(acc0[reg]);
            whT[((long)rbh * HD + f1) * NN + ncol] = __float2bfloat16(acc1[reg]);
            s = fmaf(acc0[reg], av[0][reg], s);
            s = fmaf(acc1[reg], av[1][reg], s);
            d = fmaf(acc0[reg], dv[0][reg], d);
            d = fmaf(acc1[reg], dv[1][reg], d);
        }
        s += __shfl_xor(s, 16); s += __shfl_xor(s, 32);
        d += __shfl_xor(d, 16); d += __shfl_xor(d, 32);
        if (l < 16) {
            es[(long)rbh * NN + ncol] = s;
            ed[(long)rbh * NN + ncol] = d;
        }
    }
}

// ---------------------------------------------------------------------------
// Kernel 2: fused masked softmax + MFMA aggregation (R8 structure, proven).
// num written as PACKED bf16 pairs: u32 = bf16(acc0) | bf16(acc1)<<16 at
// [ro*64 + h*16 + fcol]  (cols h*32+cc low, h*32+16+cc high).
// grid = 768 blocks (XCD-chunk swizzled), 256 threads.
// ---------------------------------------------------------------------------
__global__ __launch_bounds__(256, 3) void gat_attn_kernel(
    const unsigned* __restrict__ bm, const float* __restrict__ es,
    const float* __restrict__ ed, const __hip_bfloat16* __restrict__ whT,
    unsigned* __restrict__ num, float* __restrict__ den)
{
    // XCD-chunked bijective swizzle (768 % 8 == 0)
    const int lg = ((int)blockIdx.x % 8) * 96 + (int)blockIdx.x / 8;
    const int jh = lg & 1;
    const int it = (lg >> 1) & 15;
    const int h  = (lg >> 5) & 3;
    const int b  = (lg >> 7) & 1;
    const int r  = lg >> 8;
    const int i0 = it << 7;
    const int tid = threadIdx.x;
    const int w = tid >> 6;
    const int l = tid & 63;
    const int row = l & 15;
    const int kg  = l >> 4;
    const int f31 = l & 31;
    const int kgr = l >> 5;

    __shared__ __align__(16) short    whs[2][4][4][32][8];
    __shared__ __align__(16) unsigned bms[2][4][128];
    __shared__ __align__(16) float    eds[2][4][32];
    __shared__ float red[4];

    const int rbh = (r * BB + b) * HH + h;
    const long rbNN = (long)(r * BB + b) * NN;
    const __hip_bfloat16* whTr = whT + (long)rbh * HD * NN;
    const float* edr = ed + (long)rbh * NN;
    const int jbase = jh * (NN / 2);

#define STAGE(s, nb) do {                                                           \
        const int j0s = jbase + (s) * 128;                                          \
        gload_lds16(whTr + (long)f31 * NN + j0s + w * 32 + kgr * 8,                 \
                    &whs[nb][w][0][0][0]);                                          \
        gload_lds16(whTr + (long)f31 * NN + j0s + w * 32 + (2 + kgr) * 8,           \
                    &whs[nb][w][2][0][0]);                                          \
        gload_lds4(bm + (rbNN + i0 + l) * (NN / 32) + (j0s >> 5) + w,               \
                   &bms[nb][w][0]);                                                 \
        gload_lds4(bm + (rbNN + i0 + 64 + l) * (NN / 32) + (j0s >> 5) + w,          \
                   &bms[nb][w][64]);                                                \
        if (l < 32) gload_lds4(edr + j0s + w * 32 + l, &eds[nb][w][0]);             \
    } while (0)

    STAGE(0, 0);

    // block-wide max of ed (upper bound; cancels exactly in num/den)
    float4 m0 = ((const float4*)edr)[tid * 2];
    float4 m1 = ((const float4*)edr)[tid * 2 + 1];
    float mm = fmaxf(fmaxf(fmaxf(m0.x, m0.y), fmaxf(m0.z, m0.w)),
                     fmaxf(fmaxf(m1.x, m1.y), fmaxf(m1.z, m1.w)));
#pragma unroll
    for (int d = 1; d < 64; d <<= 1) mm = fmaxf(mm, __shfl_xor(mm, d));
    if (l == 0) red[w] = mm;
    __syncthreads();
    const float medf = fmaxf(fmaxf(red[0], red[1]), fmaxf(red[2], red[3]));

    const float esvA = es[(long)rbh * NN + i0 + w * 16 + row];
    const float esvB = es[(long)rbh * NN + i0 + 64 + w * 16 + row];
    const float xA = esvA + medf, xB = esvB + medf;
    const float MA = fmaxf(xA, LEAKY * xA), MB = fmaxf(xB, LEAKY * xB);
    const float uA = esvA - MA, vA = fmaf(LEAKY, esvA, -MA);
    const float uB = esvB - MB, vB = fmaf(LEAKY, esvB, -MB);

    f32x4 acc0A = {0,0,0,0}, acc1A = {0,0,0,0}, accDA = {0,0,0,0};
    f32x4 acc0B = {0,0,0,0}, acc1B = {0,0,0,0}, accDB = {0,0,0,0};
    bf16x8 ones;
#pragma unroll
    for (int i = 0; i < 8; ++i) ones[i] = (short)0x3F80;

    for (int s = 0; s < 8; ++s) {
        const int cb = s & 1, nb = cb ^ 1;
        if (s < 7) {
            STAGE(s + 1, nb);
            asm volatile("s_waitcnt vmcnt(5)" ::: "memory");
        } else {
            asm volatile("s_waitcnt vmcnt(0)" ::: "memory");
        }
        __builtin_amdgcn_s_barrier();
        __builtin_amdgcn_sched_barrier(0);

#pragma unroll
        for (int jc = 0; jc < 4; ++jc) {
            bf16x8 b0 = *(const bf16x8*)&whs[cb][jc][kg][row][0];
            bf16x8 b1 = *(const bf16x8*)&whs[cb][jc][kg][row + 16][0];
            float4 e0 = *(const float4*)&eds[cb][jc][kg * 8];
            float4 e1 = *(const float4*)&eds[cb][jc][kg * 8 + 4];
            const unsigned mybA = (bms[cb][jc][w * 16 + row] >> (kg * 8)) & 0xffu;
            const unsigned mybB = (bms[cb][jc][64 + w * 16 + row] >> (kg * 8)) & 0xffu;

            float ev[8];
            ev[0] = e0.x; ev[1] = e0.y; ev[2] = e0.z; ev[3] = e0.w;
            ev[4] = e1.x; ev[5] = e1.y; ev[6] = e1.z; ev[7] = e1.w;

            bf16x8 pA, pB;
#pragma unroll
            for (int c = 0; c < 8; ++c) {
                float pa = __builtin_amdgcn_exp2f(
                    fmaxf(uA + ev[c], fmaf(LEAKY, ev[c], vA)));
                float pb = __builtin_amdgcn_exp2f(
                    fmaxf(uB + ev[c], fmaf(LEAKY, ev[c], vB)));
                const int ma = ((int)(mybA << (31 - c))) >> 31;
                const int mb = ((int)(mybB << (31 - c))) >> 31;
                pa = __uint_as_float(__float_as_uint(pa) & (unsigned)ma);
                pb = __uint_as_float(__float_as_uint(pb) & (unsigned)mb);
                __hip_bfloat16 ha = __float2bfloat16(pa);
                __hip_bfloat16 hb = __float2bfloat16(pb);
                pA[c] = __builtin_bit_cast(short, ha);
                pB[c] = __builtin_bit_cast(short, hb);
            }

            acc0A = __builtin_amdgcn_mfma_f32_16x16x32_bf16(pA, b0, acc0A, 0, 0, 0);
            acc1A = __builtin_amdgcn_mfma_f32_16x16x32_bf16(pA, b1, acc1A, 0, 0, 0);
            accDA = __builtin_amdgcn_mfma_f32_16x16x32_bf16(pA, ones, accDA, 0, 0, 0);
            acc0B = __builtin_amdgcn_mfma_f32_16x16x32_bf16(pB, b0, acc0B, 0, 0, 0);
            acc1B = __builtin_amdgcn_mfma_f32_16x16x32_bf16(pB, b1, acc1B, 0, 0, 0);
            accDB = __builtin_amdgcn_mfma_f32_16x16x32_bf16(pB, ones, accDB, 0, 0, 0);
        }
        __builtin_amdgcn_s_barrier();
        __builtin_amdgcn_sched_barrier(0);
    }
#undef STAGE

    // epilogue: packed bf16 numerators + fp32 denominators
    const int fcol = l & 15;
    const int pr = r * 2 + jh;
#pragma unroll
    for (int reg = 0; reg < 4; ++reg) {
        const int orow = (l >> 4) * 4 + reg;
        const long roA = (long)pr * (BB * NN) + (long)b * NN + i0 + w * 16 + orow;
        const long roB = roA + 64;
        const unsigned wa = (unsigned)bfb(acc0A[reg]) | ((unsigned)bfb(acc1A[reg]) << 16);
        const unsigned wb_ = (unsigned)bfb(acc0B[reg]) | ((unsigned)bfb(acc1B[reg]) << 16);
        num[roA * 64 + h * 16 + fcol] = wa;
        num[roB * 64 + h * 16 + fcol] = wb_;
        if (fcol == 0) {
            den[roA * HH + h] = accDA[reg];
            den[roB * HH + h] = accDB[reg];
        }
    }
}

// ---------------------------------------------------------------------------
// Kernel 3: out = LayerNorm(H + mean_r (num_r / den_r)).  One wave per row;
// lane l owns cols c_lo = (l>>4)*32 + (l&15) and c_hi = c_lo + 16 (packed).
// ---------------------------------------------------------------------------
__global__ __launch_bounds__(256) void finalize_kernel(
    const float* __restrict__ H, const unsigned* __restrict__ num,
    const float* __restrict__ den,
    const float* __restrict__ gamma, const float* __restrict__ beta,
    float* __restrict__ out)
{
    const int w = threadIdx.x >> 6;
    const int l = threadIdx.x & 63;
    const long row = (long)blockIdx.x * 4 + w;
    const int hh = l >> 4, cc = l & 15;
    const int c_lo = hh * 32 + cc, c_hi = c_lo + 16;
    const float hx = H[row * DD + c_lo];
    const float hy = H[row * DD + c_hi];

    float ax = 0.f, ay = 0.f;
#pragma unroll
    for (int r = 0; r < RR; ++r) {
        float dsum = 0.f, nx = 0.f, ny = 0.f;
#pragma unroll
        for (int j = 0; j < 2; ++j) {
            const long ro = (long)(r * 2 + j) * (BB * NN) + row;
            dsum += den[ro * HH + hh];
            const unsigned wv = num[ro * 64 + l];
            nx += __uint_as_float(wv << 16);
            ny += __uint_as_float(wv & 0xffff0000u);
        }
        const float inv = (dsum > 0.f) ? 1.0f / dsum : 0.0f;
        ax = fmaf(nx, inv, ax);
        ay = fmaf(ny, inv, ay);
    }
    const float x0 = hx + ax * (1.0f / RR);
    const float x1 = hy + ay * (1.0f / RR);
    float s = x0 + x1, q = x0 * x0 + x1 * x1;
#pragma unroll
    for (int m = 1; m < 64; m <<= 1) {
        s += __shfl_xor(s, m);
        q += __shfl_xor(q, m);
    }
    const float mu  = s * (1.0f / DD);
    const float var = q * (1.0f / DD) - mu * mu;
    const float inv = rsqrtf(var + LN_EPS);
    out[row * DD + c_lo] = (x0 - mu) * inv * gamma[c_lo] + beta[c_lo];
    out[row * DD + c_hi] = (x1 - mu) * inv * gamma[c_hi] + beta[c_hi];
}

// ---------------------------------------------------------------------------
extern "C" void kernel_launch(void* const* d_in, const int* in_sizes, int n_in,
                              void* d_out, int out_size, void* d_ws, size_t ws_size,
                              hipStream_t stream)
{
    const float* H      = (const float*)d_in[0];
    const int*   A      = (const int*)d_in[1];
    const float* W      = (const float*)d_in[2];
    const float* a_src  = (const float*)d_in[3];
    const float* a_dst  = (const float*)d_in[4];
    const float* gamma  = (const float*)d_in[5];
    const float* beta   = (const float*)d_in[6];
    float* out = (float*)d_out;

    // workspace carve (~13.4 MB)
    char* ws = (char*)d_ws;
    unsigned* num = (unsigned*)ws;               ws += (size_t)RR * 2 * BB * NN * 64 * 4;  // 6.29 MB
    float* den = (float*)ws;                     ws += (size_t)RR * 2 * BB * NN * HH * 4;  // 393 KB
    float* es  = (float*)ws;                     ws += (size_t)RR * BB * HH * NN * 4;      // 196 KB
    float* ed  = (float*)ws;                     ws += (size_t)RR * BB * HH * NN * 4;      // 196 KB
    __hip_bfloat16* whT = (__hip_bfloat16*)ws;   ws += (size_t)RR * BB * HH * HD * NN * 2; // 3.15 MB
    unsigned* bmask = (unsigned*)ws;             ws += (size_t)RR * BB * NN * (NN / 32) * 4; // 3.15 MB

    prep_kernel<<<384 + RR * BB * NN * (NN / 32) / 256, 256, 0, stream>>>(
        H, A, W, a_src, a_dst, es, ed, whT, bmask);
    gat_attn_kernel<<<RR * BB * HH * 16 * 2, 256, 0, stream>>>(bmask, es, ed, whT, num, den);
    finalize_kernel<<<BB * NN / 4, 256, 0, stream>>>(H, num, den, gamma, beta, out);
}